// Round 1
// baseline (416.589 us; speedup 1.0000x reference)
//
#include <hip/hip_runtime.h>
#include <math.h>

#define B_ROWS 512
#define D_DIM  512
#define C_CLS  100000
#define SCALE  64.0f
#define EPSN   1e-12f

#define BN 64
#define BK 32
#define NTILE 1563          // ceil(100000/64)

typedef __attribute__((ext_vector_type(8))) short bf16x8;
typedef __attribute__((ext_vector_type(4))) float f32x4;

__device__ inline unsigned short f2bf(float f) {
    union { float f; unsigned int u; } v; v.f = f;
    unsigned int r = v.u + 0x7fffu + ((v.u >> 16) & 1u);
    return (unsigned short)(r >> 16);
}
__device__ inline float bf2f(unsigned short h) {
    union { unsigned int u; float f; } v; v.u = ((unsigned int)h) << 16;
    return v.f;
}

// ---------- normalize x rows, store bf16 (coalesced: lane, lane+64) ----------
__global__ void normalize_x(const float* __restrict__ x, unsigned short* __restrict__ xnb) {
    int row  = blockIdx.x;
    int lane = threadIdx.x;  // 64
    const float4* xr = (const float4*)(x + (size_t)row * D_DIM);
    float4 a = xr[lane];
    float4 b = xr[lane + 64];
    float ss = a.x*a.x + a.y*a.y + a.z*a.z + a.w*a.w
             + b.x*b.x + b.y*b.y + b.z*b.z + b.w*b.w;
    #pragma unroll
    for (int m = 1; m < 64; m <<= 1) ss += __shfl_xor(ss, m);
    float inv = 1.0f / fmaxf(sqrtf(ss), EPSN);
    ushort4 o0, o1;
    o0.x = f2bf(a.x*inv); o0.y = f2bf(a.y*inv); o0.z = f2bf(a.z*inv); o0.w = f2bf(a.w*inv);
    o1.x = f2bf(b.x*inv); o1.y = f2bf(b.y*inv); o1.z = f2bf(b.z*inv); o1.w = f2bf(b.w*inv);
    ushort4* orow = (ushort4*)(xnb + (size_t)row * D_DIM);
    orow[lane]      = o0;
    orow[lane + 64] = o1;
}

// ---------- fused: raw-W bf16 MFMA GEMM + on-the-fly W norms + partial softmax ----------
// BM=512 (all rows) x BN=64 per block; 512 threads = 8 waves, wave w owns rows w*64..w*64+63.
// W is read from HBM exactly once (f32), cast to bf16 during staging; sum-of-squares of each
// W row is accumulated in registers during staging; epilogue scales logits by S/||w|| (f32).
__global__ __launch_bounds__(512, 4) void gemm_fused(const unsigned short* __restrict__ xnb,
                                                     const float* __restrict__ w,
                                                     float2* __restrict__ partials) {
    __shared__ unsigned short As[B_ROWS * BK];   // 32 KB
    __shared__ unsigned short Bs[BN * BK];       // 4 KB
    __shared__ float winv_s[BN];

    int tid  = threadIdx.x;
    int c0   = blockIdx.x * BN;
    int wid  = tid >> 6;     // 0..7 : M-subtile (64 rows)
    int lane = tid & 63;
    int quad = lane >> 4;
    int lr   = lane & 15;

    f32x4 acc[4][4];
    #pragma unroll
    for (int i = 0; i < 4; i++)
        #pragma unroll
        for (int j = 0; j < 4; j++) {
            acc[i][j][0] = 0.f; acc[i][j][1] = 0.f; acc[i][j][2] = 0.f; acc[i][j][3] = 0.f;
        }

    // B staging map (constant across kt): thread owns row br, float4 chunk bq.
    int br = tid >> 3;           // 0..63 local class row
    int bq = tid & 7;            // 0..7  float4 within 32-wide K slice
    int bc = c0 + br; if (bc >= C_CLS) bc = C_CLS - 1;
    const float* wsrc = w + (size_t)bc * D_DIM + bq * 4;
    unsigned short* bdst = Bs + br * BK + bq * 4;

    // A staging map: chunk ch = i*512 + tid; row = ch>>2, koff = (ch&3)*8 ushorts.
    // LDS dest is linear (dst ushort idx = ch*8): wave-uniform base + lane*16B.
    const unsigned short* asrc[4];
    unsigned short* adst[4];
    #pragma unroll
    for (int i = 0; i < 4; i++) {
        int ch = i * 512 + tid;
        asrc[i] = xnb + (size_t)(ch >> 2) * D_DIM + (ch & 3) * 8;
        adst[i] = As + (i * 512 + wid * 64) * 8;  // + lane*8 ushorts written by HW
    }

    float ss = 0.f;

    for (int kt = 0; kt < D_DIM / BK; ++kt) {
        int k0 = kt * BK;
        __syncthreads();
        // A: async global->LDS, 4 x 16B per thread
        #pragma unroll
        for (int i = 0; i < 4; i++)
            __builtin_amdgcn_global_load_lds(
                (const __attribute__((address_space(1))) void*)(asrc[i] + k0),
                (__attribute__((address_space(3))) void*)adst[i], 16, 0, 0);
        // B: f32 load -> ss accumulate -> bf16 cast -> LDS
        float4 wv = *(const float4*)(wsrc + k0);
        ss += wv.x*wv.x + wv.y*wv.y + wv.z*wv.z + wv.w*wv.w;
        ushort4 o;
        o.x = f2bf(wv.x); o.y = f2bf(wv.y); o.z = f2bf(wv.z); o.w = f2bf(wv.w);
        *(ushort4*)bdst = o;
        __syncthreads();

        bf16x8 af[4], bf[4];
        #pragma unroll
        for (int i = 0; i < 4; i++)
            af[i] = *(const bf16x8*)(As + (wid * 64 + i * 16 + lr) * BK + quad * 8);
        #pragma unroll
        for (int j = 0; j < 4; j++)
            bf[j] = *(const bf16x8*)(Bs + (j * 16 + lr) * BK + quad * 8);
        #pragma unroll
        for (int i = 0; i < 4; i++)
            #pragma unroll
            for (int j = 0; j < 4; j++)
                acc[i][j] = __builtin_amdgcn_mfma_f32_16x16x32_bf16(af[i], bf[j], acc[i][j], 0, 0, 0);
    }

    // finish ||w||^2: 8 staging threads per row are consecutive lanes
    #pragma unroll
    for (int m = 1; m < 8; m <<= 1) ss += __shfl_xor(ss, m);
    if ((lane & 7) == 0) winv_s[wid * 8 + (lane >> 3)] = SCALE / fmaxf(sqrtf(ss), EPSN);
    __syncthreads();

    // epilogue: scale by S/||w||, per-row online-softmax partial over this block's 64 cols
    float wvs[4]; int valid[4];
    #pragma unroll
    for (int j = 0; j < 4; j++) {
        valid[j] = (c0 + j * 16 + lr) < C_CLS;
        wvs[j] = winv_s[j * 16 + lr];
    }
    #pragma unroll
    for (int i = 0; i < 4; i++) {
        #pragma unroll
        for (int r = 0; r < 4; r++) {
            int row_g = wid * 64 + i * 16 + quad * 4 + r;
            float v0 = valid[0] ? acc[i][0][r] * wvs[0] : -1e30f;
            float v1 = valid[1] ? acc[i][1][r] * wvs[1] : -1e30f;
            float v2 = valid[2] ? acc[i][2][r] * wvs[2] : -1e30f;
            float v3 = valid[3] ? acc[i][3][r] * wvs[3] : -1e30f;
            float m = fmaxf(fmaxf(v0, v1), fmaxf(v2, v3));
            #pragma unroll
            for (int msk = 1; msk < 16; msk <<= 1) m = fmaxf(m, __shfl_xor(m, msk));
            float s = expf(v0 - m) + expf(v1 - m) + expf(v2 - m) + expf(v3 - m);
            #pragma unroll
            for (int msk = 1; msk < 16; msk <<= 1) s += __shfl_xor(s, msk);
            if (lr == 0)
                partials[(size_t)row_g * NTILE + blockIdx.x] = make_float2(m, s);
        }
    }
}

// ---------- label logit from raw W (arithmetic consistent with fused GEMM) ----------
__global__ void label_logit(const unsigned short* __restrict__ xnb,
                            const float* __restrict__ w,
                            const int* __restrict__ label,
                            float* __restrict__ t) {
    int b = blockIdx.x;
    int lane = threadIdx.x;  // 64
    int lab = label[b];
    const float4*  wr = (const float4*)(w + (size_t)lab * D_DIM);
    const ushort4* xr = (const ushort4*)(xnb + (size_t)b * D_DIM);
    float dot = 0.f, ss = 0.f;
    #pragma unroll
    for (int k = 0; k < 2; k++) {
        float4  wv = wr[lane + 64 * k];
        ushort4 xv = xr[lane + 64 * k];
        ss  += wv.x*wv.x + wv.y*wv.y + wv.z*wv.z + wv.w*wv.w;
        dot += bf2f(xv.x) * bf2f(f2bf(wv.x)) + bf2f(xv.y) * bf2f(f2bf(wv.y))
             + bf2f(xv.z) * bf2f(f2bf(wv.z)) + bf2f(xv.w) * bf2f(f2bf(wv.w));
    }
    #pragma unroll
    for (int m = 1; m < 64; m <<= 1) { dot += __shfl_xor(dot, m); ss += __shfl_xor(ss, m); }
    if (lane == 0) t[b] = dot * SCALE / fmaxf(sqrtf(ss), EPSN);
}

// ---------- merge partials -> LSE -> mean NLL ----------
__global__ void reduce_loss(const float2* __restrict__ partials,
                            const float* __restrict__ t,
                            float* __restrict__ out) {
    __shared__ float sm[256], ssum[256];
    int row = blockIdx.x, tid = threadIdx.x;
    float m = -INFINITY, s = 0.f;
    for (int idx = tid; idx < NTILE; idx += 256) {
        float2 p = partials[(size_t)row * NTILE + idx];
        if (p.x > m) { s = s * expf(m - p.x) + p.y; m = p.x; }
        else         { s += p.y * expf(p.x - m); }
    }
    sm[tid] = m; ssum[tid] = s;
    __syncthreads();
    for (int off = 128; off > 0; off >>= 1) {
        if (tid < off) {
            float m2 = sm[tid + off], s2 = ssum[tid + off];
            float mm = fmaxf(m, m2);
            s = s * expf(m - mm) + s2 * expf(m2 - mm);
            m = mm;
            sm[tid] = m; ssum[tid] = s;
        }
        __syncthreads();
    }
    if (tid == 0) {
        float lse = m + logf(s);
        atomicAdd(out, (lse - t[row]) * (1.0f / (float)B_ROWS));
    }
}

extern "C" void kernel_launch(void* const* d_in, const int* in_sizes, int n_in,
                              void* d_out, int out_size, void* d_ws, size_t ws_size,
                              hipStream_t stream) {
    const float* x     = (const float*)d_in[0];
    const float* w     = (const float*)d_in[1];
    const int*   label = (const int*)d_in[2];
    float* out = (float*)d_out;

    char* ws = (char*)d_ws;
    unsigned short* xnb = (unsigned short*)ws;                 // 524288 B
    float* t            = (float*)(ws + 524288);               // 2048 B
    float2* partials    = (float2*)(ws + 526336);              // 512*1563*8 = 6402048 B (ends 6928384)

    hipMemsetAsync(d_out, 0, sizeof(float), stream);
    normalize_x<<<B_ROWS, 64, 0, stream>>>(x, xnb);
    gemm_fused<<<NTILE, 512, 0, stream>>>(xnb, w, partials);
    label_logit<<<B_ROWS, 64, 0, stream>>>(xnb, w, label, t);
    reduce_loss<<<B_ROWS, 256, 0, stream>>>(partials, t, out);
}

// Round 2
// 412.054 us; speedup vs baseline: 1.0110x; 1.0110x over previous
//
#include <hip/hip_runtime.h>
#include <math.h>

#define B_ROWS 512
#define D_DIM  512
#define C_CLS  100000
#define SCALE  64.0f
#define EPSN   1e-12f

#define BN 64
#define BK 32
#define NKT (D_DIM / BK)    // 16
#define NTILE 1563          // ceil(100000/64)

typedef __attribute__((ext_vector_type(8))) short bf16x8;
typedef __attribute__((ext_vector_type(4))) float f32x4;

__device__ inline unsigned short f2bf(float f) {
    union { float f; unsigned int u; } v; v.f = f;
    unsigned int r = v.u + 0x7fffu + ((v.u >> 16) & 1u);
    return (unsigned short)(r >> 16);
}
__device__ inline float bf2f(unsigned short h) {
    union { unsigned int u; float f; } v; v.u = ((unsigned int)h) << 16;
    return v.f;
}

// ---------- normalize x rows, store bf16 (coalesced: lane, lane+64) ----------
__global__ void normalize_x(const float* __restrict__ x, unsigned short* __restrict__ xnb) {
    int row  = blockIdx.x;
    int lane = threadIdx.x;  // 64
    const float4* xr = (const float4*)(x + (size_t)row * D_DIM);
    float4 a = xr[lane];
    float4 b = xr[lane + 64];
    float ss = a.x*a.x + a.y*a.y + a.z*a.z + a.w*a.w
             + b.x*b.x + b.y*b.y + b.z*b.z + b.w*b.w;
    #pragma unroll
    for (int m = 1; m < 64; m <<= 1) ss += __shfl_xor(ss, m);
    float inv = 1.0f / fmaxf(sqrtf(ss), EPSN);
    ushort4 o0, o1;
    o0.x = f2bf(a.x*inv); o0.y = f2bf(a.y*inv); o0.z = f2bf(a.z*inv); o0.w = f2bf(a.w*inv);
    o1.x = f2bf(b.x*inv); o1.y = f2bf(b.y*inv); o1.z = f2bf(b.z*inv); o1.w = f2bf(b.w*inv);
    ushort4* orow = (ushort4*)(xnb + (size_t)row * D_DIM);
    orow[lane]      = o0;
    orow[lane + 64] = o1;
}

// ---------- fused GEMM, 2-phase double-buffered pipeline (T3-minimum) ----------
// BM=512 (all rows) x BN=64 per block; 512 threads = 8 waves (M-split).
// W read from HBM exactly once (f32), cast to bf16 during staging, ||w||^2 fused.
// Pipeline per K-step t: stage(t+1 into buf^1) -> ds_read+MFMA(buf) -> ONE syncthreads.
// The vmcnt(0) drain at the barrier comes a full compute-phase after the loads were
// issued, hiding both global_load_lds (A) and cold-HBM f32 (W) latency.
__global__ __launch_bounds__(512, 4) void gemm_fused(const unsigned short* __restrict__ xnb,
                                                     const float* __restrict__ w,
                                                     float2* __restrict__ partials) {
    __shared__ unsigned short As[2 * B_ROWS * BK];   // 64 KB (2 x 32 KB)
    __shared__ unsigned short Bs[2 * BN * BK];       // 8 KB  (2 x 4 KB)
    __shared__ float winv_s[BN];

    int tid  = threadIdx.x;
    int c0   = blockIdx.x * BN;
    int wid  = tid >> 6;     // 0..7 : M-subtile (64 rows)
    int lane = tid & 63;
    int quad = lane >> 4;
    int lr   = lane & 15;

    f32x4 acc[4][4];
    #pragma unroll
    for (int i = 0; i < 4; i++)
        #pragma unroll
        for (int j = 0; j < 4; j++) {
            acc[i][j][0] = 0.f; acc[i][j][1] = 0.f; acc[i][j][2] = 0.f; acc[i][j][3] = 0.f;
        }

    // B staging map (constant across kt): thread owns row br, float4 chunk bq.
    int br = tid >> 3;           // 0..63 local class row
    int bq = tid & 7;            // 0..7  float4 within 32-wide K slice
    int bc = c0 + br; if (bc >= C_CLS) bc = C_CLS - 1;
    const float* wsrc = w + (size_t)bc * D_DIM + bq * 4;

    // A staging map: chunk ch = i*512 + tid; row = ch>>2, koff = (ch&3)*8 ushorts.
    const unsigned short* asrc[4];
    #pragma unroll
    for (int i = 0; i < 4; i++) {
        int ch = i * 512 + tid;
        asrc[i] = xnb + (size_t)(ch >> 2) * D_DIM + (ch & 3) * 8;
    }

    float ss = 0.f;

    // ---- prologue: stage tile 0 into buffer 0, prefetch W k-slice 1 ----
    #pragma unroll
    for (int i = 0; i < 4; i++)
        __builtin_amdgcn_global_load_lds(
            (const __attribute__((address_space(1))) void*)(asrc[i]),
            (__attribute__((address_space(3))) void*)(As + (i * 512 + wid * 64) * 8),
            16, 0, 0);
    {
        float4 wv = *(const float4*)(wsrc);
        ss += wv.x*wv.x + wv.y*wv.y + wv.z*wv.z + wv.w*wv.w;
        ushort4 o;
        o.x = f2bf(wv.x); o.y = f2bf(wv.y); o.z = f2bf(wv.z); o.w = f2bf(wv.w);
        *(ushort4*)(Bs + br * BK + bq * 4) = o;
    }
    float4 wvn = *(const float4*)(wsrc + BK);   // W k-slice 1 (register prefetch)
    __syncthreads();                            // buffer 0 ready

    for (int t = 0; t < NKT; ++t) {
        int cur = t & 1, nxt = cur ^ 1;
        // ---- stage t+1 into buf nxt (issued BEFORE compute of t) ----
        if (t + 1 < NKT) {
            int k1 = (t + 1) * BK;
            #pragma unroll
            for (int i = 0; i < 4; i++)
                __builtin_amdgcn_global_load_lds(
                    (const __attribute__((address_space(1))) void*)(asrc[i] + k1),
                    (__attribute__((address_space(3))) void*)(As + nxt * 16384 + (i * 512 + wid * 64) * 8),
                    16, 0, 0);
            float4 wv = wvn;                    // W[t+1], loaded one iteration ago
            if (t + 2 < NKT) wvn = *(const float4*)(wsrc + (t + 2) * BK);
            ss += wv.x*wv.x + wv.y*wv.y + wv.z*wv.z + wv.w*wv.w;
            ushort4 o;
            o.x = f2bf(wv.x); o.y = f2bf(wv.y); o.z = f2bf(wv.z); o.w = f2bf(wv.w);
            *(ushort4*)(Bs + nxt * 2048 + br * BK + bq * 4) = o;
        }
        // ---- compute tile t from buf cur ----
        bf16x8 af[4], bf[4];
        #pragma unroll
        for (int i = 0; i < 4; i++)
            af[i] = *(const bf16x8*)(As + cur * 16384 + (wid * 64 + i * 16 + lr) * BK + quad * 8);
        #pragma unroll
        for (int j = 0; j < 4; j++)
            bf[j] = *(const bf16x8*)(Bs + cur * 2048 + (j * 16 + lr) * BK + quad * 8);
        #pragma unroll
        for (int i = 0; i < 4; i++)
            #pragma unroll
            for (int j = 0; j < 4; j++)
                acc[i][j] = __builtin_amdgcn_mfma_f32_16x16x32_bf16(af[i], bf[j], acc[i][j], 0, 0, 0);
        __syncthreads();   // drains vmcnt/lgkmcnt: buf nxt ready, buf cur free
    }

    // finish ||w||^2: 8 staging threads per row are consecutive lanes
    #pragma unroll
    for (int m = 1; m < 8; m <<= 1) ss += __shfl_xor(ss, m);
    if ((lane & 7) == 0) winv_s[wid * 8 + (lane >> 3)] = SCALE / fmaxf(sqrtf(ss), EPSN);
    __syncthreads();

    // epilogue: scale by S/||w||, per-row online-softmax partial over this block's 64 cols
    float wvs[4]; int valid[4];
    #pragma unroll
    for (int j = 0; j < 4; j++) {
        valid[j] = (c0 + j * 16 + lr) < C_CLS;
        wvs[j] = winv_s[j * 16 + lr];
    }
    #pragma unroll
    for (int i = 0; i < 4; i++) {
        #pragma unroll
        for (int r = 0; r < 4; r++) {
            int row_g = wid * 64 + i * 16 + quad * 4 + r;
            float v0 = valid[0] ? acc[i][0][r] * wvs[0] : -1e30f;
            float v1 = valid[1] ? acc[i][1][r] * wvs[1] : -1e30f;
            float v2 = valid[2] ? acc[i][2][r] * wvs[2] : -1e30f;
            float v3 = valid[3] ? acc[i][3][r] * wvs[3] : -1e30f;
            float m = fmaxf(fmaxf(v0, v1), fmaxf(v2, v3));
            #pragma unroll
            for (int msk = 1; msk < 16; msk <<= 1) m = fmaxf(m, __shfl_xor(m, msk));
            float s = expf(v0 - m) + expf(v1 - m) + expf(v2 - m) + expf(v3 - m);
            #pragma unroll
            for (int msk = 1; msk < 16; msk <<= 1) s += __shfl_xor(s, msk);
            if (lr == 0)
                partials[(size_t)row_g * NTILE + blockIdx.x] = make_float2(m, s);
        }
    }
}

// ---------- label logit from raw W (arithmetic consistent with fused GEMM) ----------
__global__ void label_logit(const unsigned short* __restrict__ xnb,
                            const float* __restrict__ w,
                            const int* __restrict__ label,
                            float* __restrict__ t) {
    int b = blockIdx.x;
    int lane = threadIdx.x;  // 64
    int lab = label[b];
    const float4*  wr = (const float4*)(w + (size_t)lab * D_DIM);
    const ushort4* xr = (const ushort4*)(xnb + (size_t)b * D_DIM);
    float dot = 0.f, ss = 0.f;
    #pragma unroll
    for (int k = 0; k < 2; k++) {
        float4  wv = wr[lane + 64 * k];
        ushort4 xv = xr[lane + 64 * k];
        ss  += wv.x*wv.x + wv.y*wv.y + wv.z*wv.z + wv.w*wv.w;
        dot += bf2f(xv.x) * bf2f(f2bf(wv.x)) + bf2f(xv.y) * bf2f(f2bf(wv.y))
             + bf2f(xv.z) * bf2f(f2bf(wv.z)) + bf2f(xv.w) * bf2f(f2bf(wv.w));
    }
    #pragma unroll
    for (int m = 1; m < 64; m <<= 1) { dot += __shfl_xor(dot, m); ss += __shfl_xor(ss, m); }
    if (lane == 0) t[b] = dot * SCALE / fmaxf(sqrtf(ss), EPSN);
}

// ---------- merge partials -> LSE -> mean NLL ----------
__global__ void reduce_loss(const float2* __restrict__ partials,
                            const float* __restrict__ t,
                            float* __restrict__ out) {
    __shared__ float sm[256], ssum[256];
    int row = blockIdx.x, tid = threadIdx.x;
    float m = -INFINITY, s = 0.f;
    for (int idx = tid; idx < NTILE; idx += 256) {
        float2 p = partials[(size_t)row * NTILE + idx];
        if (p.x > m) { s = s * expf(m - p.x) + p.y; m = p.x; }
        else         { s += p.y * expf(p.x - m); }
    }
    sm[tid] = m; ssum[tid] = s;
    __syncthreads();
    for (int off = 128; off > 0; off >>= 1) {
        if (tid < off) {
            float m2 = sm[tid + off], s2 = ssum[tid + off];
            float mm = fmaxf(m, m2);
            s = s * expf(m - mm) + s2 * expf(m2 - mm);
            m = mm;
            sm[tid] = m; ssum[tid] = s;
        }
        __syncthreads();
    }
    if (tid == 0) {
        float lse = m + logf(s);
        atomicAdd(out, (lse - t[row]) * (1.0f / (float)B_ROWS));
    }
}

extern "C" void kernel_launch(void* const* d_in, const int* in_sizes, int n_in,
                              void* d_out, int out_size, void* d_ws, size_t ws_size,
                              hipStream_t stream) {
    const float* x     = (const float*)d_in[0];
    const float* w     = (const float*)d_in[1];
    const int*   label = (const int*)d_in[2];
    float* out = (float*)d_out;

    char* ws = (char*)d_ws;
    unsigned short* xnb = (unsigned short*)ws;                 // 524288 B
    float* t            = (float*)(ws + 524288);               // 2048 B
    float2* partials    = (float2*)(ws + 526336);              // 512*1563*8 = 6402048 B (ends 6928384)

    hipMemsetAsync(d_out, 0, sizeof(float), stream);
    normalize_x<<<B_ROWS, 64, 0, stream>>>(x, xnb);
    gemm_fused<<<NTILE, 512, 0, stream>>>(xnb, w, partials);
    label_logit<<<B_ROWS, 64, 0, stream>>>(xnb, w, label, t);
    reduce_loss<<<B_ROWS, 256, 0, stream>>>(partials, t, out);
}